// Round 1
// baseline (658.181 us; speedup 1.0000x reference)
//
#include <hip/hip_runtime.h>
#include <cstdint>
#include <cstddef>

#define B_ 4
#define C_ 384
#define H_ 224
#define W_ 224
#define HH 28
#define WW 28
#define HW_ (H_*W_)
#define M_ (HH*WW)
#define SCALE_ 0.05103103630798288f   // 1/sqrt(384)
#define EPS_ 1e-12f

__device__ __forceinline__ unsigned short f2bf(float f) {
    union { float f; unsigned int u; } v; v.f = f;
    unsigned int r = v.u + 0x7FFFu + ((v.u >> 16) & 1u);
    return (unsigned short)(r >> 16);
}
__device__ __forceinline__ float bf2f(unsigned short h) {
    union { unsigned int u; float f; } v; v.u = ((unsigned int)h) << 16;
    return v.f;
}

// ---------------------------------------------------------------------------
// K1: 8x8 average pool. One block per (b, c, yy) row-stripe of 8 rows.
// Threads 0..223 each sum one column (coalesced), then 28 threads reduce
// groups of 8 columns. stoken layout: [b][yy][xx][c] (contiguous c).
// ---------------------------------------------------------------------------
__global__ __launch_bounds__(256) void k_pool(const float* __restrict__ x,
                                              float* __restrict__ stoken) {
    int bid = blockIdx.x;
    int yy = bid % HH;
    int t  = bid / HH;
    int c  = t % C_;
    int b  = t / C_;
    __shared__ float colsum[W_];
    int q = threadIdx.x;
    if (q < W_) {
        const float* base = x + ((size_t)(b * C_ + c) * H_ + yy * 8) * W_ + q;
        float s = 0.f;
        #pragma unroll
        for (int p = 0; p < 8; ++p) s += base[(size_t)p * W_];
        colsum[q] = s;
    }
    __syncthreads();
    if (q < WW) {
        float s = 0.f;
        #pragma unroll
        for (int j = 0; j < 8; ++j) s += colsum[q * 8 + j];
        stoken[(((size_t)b * HH + yy) * WW + q) * C_ + c] = s * (1.f / 64.f);
    }
}

// ---------------------------------------------------------------------------
// K2: iteration 0. One block (256 threads = 4 waves) per (b, patch).
//  phase0: load 9-neighbor st_unf (zero-padded) into LDS as bf16
//  phase1: QK^T partials per wave c-chunk; stage pixels as bf16 in LDS
//  softmax over 9 per pixel row
//  affinity column-sums -> atomic fold into norm
//  phase2: st[c][n] = sum_l pix[l][c]*aff[l][n] -> atomic fold into raw
// ---------------------------------------------------------------------------
__global__ __launch_bounds__(256) void k_iter0(const float* __restrict__ x,
                                               const float* __restrict__ stoken,
                                               float* __restrict__ raw,
                                               float* __restrict__ norm) {
    int bid = blockIdx.x;
    int m = bid % M_;
    int b = bid / M_;
    int py = m / WW, pxx = m % WW;
    int tid = threadIdx.x;
    int w = tid >> 6, l = tid & 63;
    int pp = l >> 3, qq = l & 7;

    __shared__ unsigned short pixs[C_][66];  // bf16 pixels [c][l], pad->66 (2-way banks, free)
    __shared__ float sbuf[2304];             // phase0/1: bf16 st_unf (3456 ushort = 6912B); then qkred[4*64*9]
    __shared__ float aff[64][10];

    unsigned short* stub = (unsigned short*)sbuf;

    // phase 0: st_unf
    for (int idx = tid; idx < 9 * C_; idx += 256) {
        int n = idx / C_, c = idx - n * C_;
        int yy = py + n / 3 - 1, xx = pxx + n % 3 - 1;
        float v = 0.f;
        if (yy >= 0 && yy < HH && xx >= 0 && xx < WW)
            v = stoken[(((size_t)b * HH + yy) * WW + xx) * C_ + c];
        stub[idx] = f2bf(v);
    }
    __syncthreads();

    // phase 1: QK partials; stage pixels
    const float* pxbase = x + (size_t)b * C_ * HW_ + (size_t)(py * 8 + pp) * W_ + (pxx * 8 + qq);
    float acc[9];
    #pragma unroll
    for (int n = 0; n < 9; ++n) acc[n] = 0.f;
    int c0 = w * 96;
    #pragma unroll 4
    for (int c = c0; c < c0 + 96; ++c) {
        float pv = pxbase[(size_t)c * HW_];
        pixs[c][l] = f2bf(pv);
        #pragma unroll
        for (int n = 0; n < 9; ++n) acc[n] += pv * bf2f(stub[n * C_ + c]);
    }
    __syncthreads();                 // all stub reads done; pixs complete
    float* qkred = sbuf;             // reuse (overwrites stub)
    #pragma unroll
    for (int n = 0; n < 9; ++n) qkred[tid * 9 + n] = acc[n];
    __syncthreads();

    if (tid < 64) {
        float s[9];
        #pragma unroll
        for (int n = 0; n < 9; ++n)
            s[n] = (qkred[(0 * 64 + tid) * 9 + n] + qkred[(1 * 64 + tid) * 9 + n] +
                    qkred[(2 * 64 + tid) * 9 + n] + qkred[(3 * 64 + tid) * 9 + n]) * SCALE_;
        float mx = s[0];
        #pragma unroll
        for (int n = 1; n < 9; ++n) mx = fmaxf(mx, s[n]);
        float den = 0.f;
        #pragma unroll
        for (int n = 0; n < 9; ++n) { float e = __expf(s[n] - mx); den += e; s[n] = e; }
        float inv = 1.f / den;
        #pragma unroll
        for (int n = 0; n < 9; ++n) aff[tid][n] = s[n] * inv;
    }
    __syncthreads();

    // fold-normalizer: affsum per n -> scatter to norm
    if (tid < 9) {
        float s = 0.f;
        for (int ll = 0; ll < 64; ++ll) s += aff[ll][tid];
        int ty = py + tid / 3 - 1, tx = pxx + tid % 3 - 1;
        if (ty >= 0 && ty < HH && tx >= 0 && tx < WW)
            atomicAdd(&norm[((size_t)b * HH + ty) * WW + tx], s);
    }

    // phase 2: st per channel, scatter-fold into raw
    for (int c = tid; c < C_; c += 256) {
        float a2[9];
        #pragma unroll
        for (int n = 0; n < 9; ++n) a2[n] = 0.f;
        for (int ll = 0; ll < 64; ++ll) {
            float pv = bf2f(pixs[c][ll]);
            #pragma unroll
            for (int n = 0; n < 9; ++n) a2[n] += pv * aff[ll][n];
        }
        #pragma unroll
        for (int n = 0; n < 9; ++n) {
            int ty = py + n / 3 - 1, tx = pxx + n % 3 - 1;
            if (ty >= 0 && ty < HH && tx >= 0 && tx < WW)
                atomicAdd(&raw[(((size_t)b * HH + ty) * WW + tx) * C_ + c], a2[n]);
        }
    }
}

// ---------------------------------------------------------------------------
// K3: iteration 1 + broadcast. One block per (b, patch).
// st_unf = raw/(norm+eps); recompute affinity; out[c][l] = sum_n st_unf*aff.
// ---------------------------------------------------------------------------
__global__ __launch_bounds__(256) void k_final(const float* __restrict__ x,
                                               const float* __restrict__ raw,
                                               const float* __restrict__ norm,
                                               float* __restrict__ out) {
    int bid = blockIdx.x;
    int m = bid % M_;
    int b = bid / M_;
    int py = m / WW, pxx = m % WW;
    int tid = threadIdx.x;
    int w = tid >> 6, l = tid & 63;
    int pp = l >> 3, qq = l & 7;

    __shared__ unsigned short stub[9 * C_];
    __shared__ float qkred[4 * 64 * 9];
    __shared__ float aff[64][10];

    // st_unf of refined stokens (divide by fold-norm on load)
    for (int idx = tid; idx < 9 * C_; idx += 256) {
        int n = idx / C_, c = idx - n * C_;
        int yy = py + n / 3 - 1, xx = pxx + n % 3 - 1;
        float v = 0.f;
        if (yy >= 0 && yy < HH && xx >= 0 && xx < WW) {
            size_t cell = ((size_t)b * HH + yy) * WW + xx;
            v = raw[cell * C_ + c] / (norm[cell] + EPS_);
        }
        stub[idx] = f2bf(v);
    }
    __syncthreads();

    const float* pxbase = x + (size_t)b * C_ * HW_ + (size_t)(py * 8 + pp) * W_ + (pxx * 8 + qq);
    float acc[9];
    #pragma unroll
    for (int n = 0; n < 9; ++n) acc[n] = 0.f;
    int c0 = w * 96;
    #pragma unroll 4
    for (int c = c0; c < c0 + 96; ++c) {
        float pv = pxbase[(size_t)c * HW_];
        #pragma unroll
        for (int n = 0; n < 9; ++n) acc[n] += pv * bf2f(stub[n * C_ + c]);
    }
    #pragma unroll
    for (int n = 0; n < 9; ++n) qkred[tid * 9 + n] = acc[n];
    __syncthreads();

    if (tid < 64) {
        float s[9];
        #pragma unroll
        for (int n = 0; n < 9; ++n)
            s[n] = (qkred[(0 * 64 + tid) * 9 + n] + qkred[(1 * 64 + tid) * 9 + n] +
                    qkred[(2 * 64 + tid) * 9 + n] + qkred[(3 * 64 + tid) * 9 + n]) * SCALE_;
        float mx = s[0];
        #pragma unroll
        for (int n = 1; n < 9; ++n) mx = fmaxf(mx, s[n]);
        float den = 0.f;
        #pragma unroll
        for (int n = 0; n < 9; ++n) { float e = __expf(s[n] - mx); den += e; s[n] = e; }
        float inv = 1.f / den;
        #pragma unroll
        for (int n = 0; n < 9; ++n) aff[tid][n] = s[n] * inv;
    }
    __syncthreads();

    // broadcast: out[b][c][py*8+pp][pxx*8+qq] = sum_n st_unf[n][c]*aff[l][n]
    float areg[9];
    #pragma unroll
    for (int n = 0; n < 9; ++n) areg[n] = aff[l][n];
    float* obase = out + (size_t)b * C_ * HW_ + (size_t)(py * 8 + pp) * W_ + (pxx * 8 + qq);
    #pragma unroll 4
    for (int c = c0; c < c0 + 96; ++c) {
        float v = 0.f;
        #pragma unroll
        for (int n = 0; n < 9; ++n) v += bf2f(stub[n * C_ + c]) * areg[n];
        obase[(size_t)c * HW_] = v;
    }
}

extern "C" void kernel_launch(void* const* d_in, const int* in_sizes, int n_in,
                              void* d_out, int out_size, void* d_ws, size_t ws_size,
                              hipStream_t stream) {
    const float* x = (const float*)d_in[0];
    float* out = (float*)d_out;

    const size_t STN = (size_t)B_ * HH * WW * C_;   // 1,204,224 floats
    float* stoken = (float*)d_ws;
    float* raw    = stoken + STN;
    float* norm   = raw + STN;                      // B*HH*WW floats

    hipMemsetAsync(raw, 0, STN * sizeof(float), stream);
    hipMemsetAsync(norm, 0, (size_t)B_ * HH * WW * sizeof(float), stream);

    k_pool <<<B_ * C_ * HH, 256, 0, stream>>>(x, stoken);
    k_iter0<<<B_ * M_,      256, 0, stream>>>(x, stoken, raw, norm);
    k_final<<<B_ * M_,      256, 0, stream>>>(x, raw, norm, out);
}